// Round 10
// baseline (377.325 us; speedup 1.0000x reference)
//
#include <hip/hip_runtime.h>

typedef unsigned short u16;
typedef unsigned int u32;

__device__ __forceinline__ float bf2f(u16 u) {
    return __uint_as_float(((u32)u) << 16);
}
__device__ __forceinline__ u16 f2bf(float f) {
    u32 u = __float_as_uint(f);
    u32 r = (u + 0x7fffu + ((u >> 16) & 1u)) >> 16;
    return (u16)r;
}
__device__ __forceinline__ float ldf(const void* p, int i, int isf32) {
    return isf32 ? ((const float*)p)[i] : bf2f(((const u16*)p)[i]);
}

// ---- canonical f32 param block offsets (in floats) ----
#define P_W1   0        // 128x64
#define P_W2   8192     // 64x64
#define P_B1   12288    // 64
#define P_B2   12352    // 64
#define P_A1W  12416    // 144
#define P_A1B  12560    // 1
#define P_T1W  12561    // 16
#define P_T1B  12577    // 16
#define P_A2W  12593    // 144
#define P_A2B  12737    // 1
#define P_T2W  12738    // 16
#define P_T2B  12754    // 16
#define P_CLSW 12770    // 128 (64x2)
#define P_CLSB 12898    // 2
#define P_TOT  12900

#define CH   4096       // edges per sort chunk
#define NCHB 256        // padded bucket count; bucket = dst>>9 (<=195)
#define CAP  512        // aggregate per-node LDS cache

// ---------------------------------------------------------------------------
// Detect f32 vs bf16 storage of float tensors (round-1 notes).
// ---------------------------------------------------------------------------
__global__ __launch_bounds__(256) void detect_dtype(
    const u32* __restrict__ xw, int nwords, int* __restrict__ flag)
{
    __shared__ int sbad;
    if (threadIdx.x == 0) sbad = 0;
    __syncthreads();
    int bad = 0;
    for (int i = threadIdx.x; i < nwords; i += 256) {
        u32 w = xw[i];
        int ea = (w >> 7) & 0xff;
        if (ea >= 0xF0) bad = 1;
    }
    if (bad) sbad = 1;
    __syncthreads();
    if (threadIdx.x == 0) flag[0] = sbad;
}

// ---------------------------------------------------------------------------
// Convert all small parameter tensors into one f32 param block.
// ---------------------------------------------------------------------------
__global__ __launch_bounds__(256) void prep_params(
    const void* l1w, const void* l1b, const void* a1w, const void* a1b,
    const void* t1w, const void* t1b, const void* l2w, const void* l2b,
    const void* a2w, const void* a2b, const void* t2w, const void* t2b,
    const void* clsw, const void* clsb,
    const int* __restrict__ flag, float* __restrict__ P)
{
    const int f = flag[0];
    const int t = blockIdx.x * 256 + threadIdx.x;
    const int stride = gridDim.x * 256;
#define SEG(src, off, cnt) for (int i = t; i < (cnt); i += stride) P[(off) + i] = ldf(src, i, f)
    SEG(l1w, P_W1, 8192);
    SEG(l2w, P_W2, 4096);
    SEG(l1b, P_B1, 64);
    SEG(l2b, P_B2, 64);
    SEG(a1w, P_A1W, 144);
    SEG(a1b, P_A1B, 1);
    SEG(t1w, P_T1W, 16);
    SEG(t1b, P_T1B, 16);
    SEG(a2w, P_A2W, 144);
    SEG(a2b, P_A2B, 1);
    SEG(t2w, P_T2W, 16);
    SEG(t2b, P_T2B, 16);
    SEG(clsw, P_CLSW, 128);
    SEG(clsb, P_CLSB, 2);
#undef SEG
}

// ---------------------------------------------------------------------------
// Node transform as tiled GEMM: h = x @ W + b packed bf16; fused si/sj.
// XMODE: 0 = runtime flag (f32/bf16), 1 = f32 input, 2 = bf16 input.
// ---------------------------------------------------------------------------
template<int K, int XMODE>
__global__ __launch_bounds__(256) void node_gemm(
    const void* __restrict__ xin, const float* __restrict__ P,
    int WOFF, int BOFF, int AOFF, const int* __restrict__ flag,
    u32* __restrict__ houtb, float* __restrict__ si, float* __restrict__ sj,
    int nnodes)
{
    __shared__ float Ws[K * 64];
    __shared__ float As[32][66];
    const int t = threadIdx.x;
    const int tx = t & 15;
    const int ty = t >> 4;
    const int base = blockIdx.x * 64;
    const bool xf32 = (XMODE == 0) ? (flag[0] != 0) : (XMODE == 1);

    for (int i = t * 4; i < K * 64; i += 1024)
        *(float4*)&Ws[i] = *(const float4*)&P[WOFF + i];

    float acc[4][4];
    #pragma unroll
    for (int r = 0; r < 4; ++r)
        #pragma unroll
        for (int c = 0; c < 4; ++c) acc[r][c] = 0.f;

    for (int k0 = 0; k0 < K; k0 += 32) {
        __syncthreads();
        if (xf32) {
            #pragma unroll
            for (int it = 0; it < 2; ++it) {
                int idx = t + it * 256;
                int row = idx >> 3, cq = (idx & 7) * 4;
                float4 v = make_float4(0.f, 0.f, 0.f, 0.f);
                if (base + row < nnodes)
                    v = *(const float4*)&((const float*)xin)[(size_t)(base + row) * K + k0 + cq];
                As[cq + 0][row] = v.x; As[cq + 1][row] = v.y;
                As[cq + 2][row] = v.z; As[cq + 3][row] = v.w;
            }
        } else {
            int row = t >> 2, q = (t & 3) * 8;
            uint4 v = make_uint4(0u, 0u, 0u, 0u);
            if (base + row < nnodes)
                v = *(const uint4*)&((const u16*)xin)[(size_t)(base + row) * K + k0 + q];
            As[q + 0][row] = bf2f((u16)(v.x & 0xffffu));
            As[q + 1][row] = bf2f((u16)(v.x >> 16));
            As[q + 2][row] = bf2f((u16)(v.y & 0xffffu));
            As[q + 3][row] = bf2f((u16)(v.y >> 16));
            As[q + 4][row] = bf2f((u16)(v.z & 0xffffu));
            As[q + 5][row] = bf2f((u16)(v.z >> 16));
            As[q + 6][row] = bf2f((u16)(v.w & 0xffffu));
            As[q + 7][row] = bf2f((u16)(v.w >> 16));
        }
        __syncthreads();

        #pragma unroll
        for (int k = 0; k < 32; ++k) {
            float2 a01 = *(float2*)&As[k][ty * 4];
            float2 a23 = *(float2*)&As[k][ty * 4 + 2];
            float4 b = *(float4*)&Ws[(k0 + k) * 64 + tx * 4];
            float a[4] = { a01.x, a01.y, a23.x, a23.y };
            float bb[4] = { b.x, b.y, b.z, b.w };
            #pragma unroll
            for (int r = 0; r < 4; ++r)
                #pragma unroll
                for (int c = 0; c < 4; ++c)
                    acc[r][c] = fmaf(a[r], bb[c], acc[r][c]);
        }
    }

    #pragma unroll
    for (int c = 0; c < 4; ++c) {
        float bc = P[BOFF + tx * 4 + c];
        #pragma unroll
        for (int r = 0; r < 4; ++r) acc[r][c] += bc;
    }

    float vi[4], vj[4];
    #pragma unroll
    for (int r = 0; r < 4; ++r) {
        float a_i = 0.f, a_j = 0.f;
        #pragma unroll
        for (int c = 0; c < 4; ++c) {
            a_i = fmaf(acc[r][c], P[AOFF + tx * 4 + c], a_i);
            a_j = fmaf(acc[r][c], P[AOFF + 64 + tx * 4 + c], a_j);
        }
        vi[r] = a_i; vj[r] = a_j;
    }
    #pragma unroll
    for (int o = 1; o < 16; o <<= 1) {
        #pragma unroll
        for (int r = 0; r < 4; ++r) {
            vi[r] += __shfl_xor(vi[r], o);
            vj[r] += __shfl_xor(vj[r], o);
        }
    }

    #pragma unroll
    for (int r = 0; r < 4; ++r) {
        int node = base + ty * 4 + r;
        if (node < nnodes) {
            u32 w0 = (u32)f2bf(acc[r][0]) | ((u32)f2bf(acc[r][1]) << 16);
            u32 w1 = (u32)f2bf(acc[r][2]) | ((u32)f2bf(acc[r][3]) << 16);
            *(uint2*)&houtb[(size_t)node * 32 + tx * 2] = make_uint2(w0, w1);
            if (tx == 0) { si[node] = vi[r]; sj[node] = vj[r]; }
        }
    }
}

// ---------------------------------------------------------------------------
// Counting sort pass 1: per-chunk bucket histogram (bucket = dst>>9).
// ---------------------------------------------------------------------------
__global__ __launch_bounds__(256) void count_chunks(
    const int* __restrict__ eid, int* __restrict__ chunkhist, int E)
{
    __shared__ int hist[NCHB];
    const int t = threadIdx.x, c = blockIdx.x;
    hist[t] = 0;
    __syncthreads();
    const int base = c * CH;
    #pragma unroll
    for (int i = 0; i < CH / 256; ++i) {
        int e = base + t + i * 256;
        if (e < E) atomicAdd(&hist[eid[e] >> 9], 1);
    }
    __syncthreads();
    chunkhist[c * NCHB + t] = hist[t];
}

// ---------------------------------------------------------------------------
// Scan stage A: one block per bucket; Hillis-Steele over chunk entries.
// ---------------------------------------------------------------------------
__global__ __launch_bounds__(256) void scan_chunks(
    int* __restrict__ chunkhist, int* __restrict__ buckettot, int nchunks)
{
    __shared__ int s[512];
    const int b = blockIdx.x, t = threadIdx.x;
    int v0 = (t < nchunks) ? chunkhist[(size_t)t * NCHB + b] : 0;
    int v1 = (t + 256 < nchunks) ? chunkhist[(size_t)(t + 256) * NCHB + b] : 0;
    s[t] = v0; s[t + 256] = v1;
    __syncthreads();
    for (int off = 1; off < 512; off <<= 1) {
        int x0 = (t >= off) ? s[t - off] : 0;
        int x1 = s[t + 256 - off];
        __syncthreads();
        s[t] += x0; s[t + 256] += x1;
        __syncthreads();
    }
    if (t < nchunks) chunkhist[(size_t)t * NCHB + b] = s[t] - v0;
    if (t + 256 < nchunks) chunkhist[(size_t)(t + 256) * NCHB + b] = s[t + 256] - v1;
    if (t == 255) buckettot[b] = s[511];
}

// ---------------------------------------------------------------------------
// Scan stage B: 1 tiny block. Exclusive scan of bucket totals.
// ---------------------------------------------------------------------------
__global__ __launch_bounds__(256) void bucket_start_scan(
    const int* __restrict__ buckettot, int* __restrict__ bucketstart,
    int* __restrict__ offs, int N)
{
    __shared__ int s[NCHB];
    const int b = threadIdx.x;
    int v = buckettot[b];
    s[b] = v;
    __syncthreads();
    for (int off = 1; off < NCHB; off <<= 1) {
        int x = (b >= off) ? s[b - off] : 0;
        __syncthreads();
        s[b] += x;
        __syncthreads();
    }
    bucketstart[b] = s[b] - v;
    if (b == NCHB - 1) { bucketstart[NCHB] = s[b]; offs[N] = s[b]; }
}

// ---------------------------------------------------------------------------
// Counting sort pass 2: sort each chunk in LDS, coalesced flush to the
// bucket-sorted staging array. Payload (src | ldst<<17, t_bits).
// ---------------------------------------------------------------------------
__global__ __launch_bounds__(256) void place_chunks(
    const int* __restrict__ ei, const void* __restrict__ et,
    const int* __restrict__ flag, const int* __restrict__ chunkhist,
    const int* __restrict__ bucketstart, int2* __restrict__ staging, int E)
{
    __shared__ int2 sorted[CH];            // 32 KB
    __shared__ unsigned char bno[CH];      // 4 KB
    __shared__ int hist[NCHB], lstart[NCHB], cur[NCHB], gb[NCHB];
    const int t = threadIdx.x, c = blockIdx.x;
    const int base = c * CH;
    const int f = flag[0];
    hist[t] = 0;
    gb[t] = bucketstart[t] + chunkhist[c * NCHB + t];
    __syncthreads();
    #pragma unroll
    for (int i = 0; i < CH / 256; ++i) {
        int e = base + t + i * 256;
        if (e < E) atomicAdd(&hist[ei[E + e] >> 9], 1);
    }
    __syncthreads();
    int v = hist[t];
    lstart[t] = v;
    __syncthreads();
    for (int off = 1; off < NCHB; off <<= 1) {
        int x = (t >= off) ? lstart[t - off] : 0;
        __syncthreads();
        lstart[t] += x;
        __syncthreads();
    }
    int ex = lstart[t] - v;   // exclusive local start
    __syncthreads();
    lstart[t] = ex;
    cur[t] = ex;
    __syncthreads();
    #pragma unroll
    for (int i = 0; i < CH / 256; ++i) {
        int e = base + t + i * 256;
        if (e < E) {
            int s_ = ei[e], d = ei[E + e];
            float tt = ldf(et, e, f);
            int b = d >> 9;
            int p = atomicAdd(&cur[b], 1);
            sorted[p] = make_int2(s_ | ((d & 511) << 17), __float_as_int(tt));
            bno[p] = (unsigned char)b;
        }
    }
    __syncthreads();
    const int cnt_tot = min(CH, E - base);
    for (int idx = t; idx < cnt_tot; idx += 256) {
        int b = bno[idx];
        staging[gb[b] + (idx - lstart[b])] = sorted[idx];
    }
}

// ---------------------------------------------------------------------------
// Bin within bucket + temporal precompute: per-node LDS histogram + scan ->
// offs; place per-layer (src, td+bias) into csrA/csrB. The 32 sins per edge
// run here at full 64-lane efficiency under memory latency, so the hot
// aggregates never touch sin.
// ---------------------------------------------------------------------------
__global__ __launch_bounds__(256) void bin_edges(
    const int2* __restrict__ staging, const int* __restrict__ bucketstart,
    const float* __restrict__ P, int* __restrict__ offs,
    int2* __restrict__ csrA, int2* __restrict__ csrB, int N)
{
    __shared__ int cnt[512], loc[512];
    const int b = blockIdx.x, t = threadIdx.x;
    const int beg = bucketstart[b], end = bucketstart[b + 1];
    const int nstart = b << 9;
    cnt[t] = 0; cnt[t + 256] = 0;
    __syncthreads();
    for (int i = beg + t; i < end; i += 256)
        atomicAdd(&cnt[(((u32)staging[i].x) >> 17) & 511], 1);
    __syncthreads();
    int v0 = cnt[t], v1 = cnt[t + 256];
    loc[t] = v0; loc[t + 256] = v1;
    __syncthreads();
    for (int off = 1; off < 512; off <<= 1) {
        int x0 = (t >= off) ? loc[t - off] : 0;
        int x1 = loc[t + 256 - off];
        __syncthreads();
        loc[t] += x0; loc[t + 256] += x1;
        __syncthreads();
    }
    int cur0 = beg + loc[t] - v0;
    int cur1 = beg + loc[t + 256] - v1;
    if (nstart + t < N) offs[nstart + t] = cur0;
    if (nstart + t + 256 < N) offs[nstart + t + 256] = cur1;
    cnt[t] = cur0; cnt[t + 256] = cur1;
    __syncthreads();

    float tw1[16], tb1[16], aw1[16], tw2[16], tb2[16], aw2[16];
    #pragma unroll
    for (int k = 0; k < 16; ++k) {
        tw1[k] = P[P_T1W + k]; tb1[k] = P[P_T1B + k]; aw1[k] = P[P_A1W + 128 + k];
        tw2[k] = P[P_T2W + k]; tb2[k] = P[P_T2B + k]; aw2[k] = P[P_A2W + 128 + k];
    }
    const float ab1 = P[P_A1B], ab2 = P[P_A2B];

    for (int i = beg + t; i < end; i += 256) {
        int2 e = staging[i];
        int slot = atomicAdd(&cnt[(((u32)e.x) >> 17) & 511], 1);
        float tt = __int_as_float(e.y);
        float td1 = ab1, td2 = ab2;
        #pragma unroll
        for (int k = 0; k < 16; ++k) {
            td1 += __sinf(fmaf(tt, tw1[k], tb1[k])) * aw1[k];
            td2 += __sinf(fmaf(tt, tw2[k], tb2[k])) * aw2[k];
        }
        int srcv = e.x & 0x1ffff;
        csrA[slot] = make_int2(srcv, __float_as_int(td1));
        csrB[slot] = make_int2(srcv, __float_as_int(td2));
    }
}

// ---------------------------------------------------------------------------
// Aggregate: wave per node. alpha = leaky(si[node] + sj[src] + tdb) — no sin.
// Denominator pass converts the LDS cache from alpha to e = exp(alpha - m),
// so phase B does no expf. MODE 0 -> packed-bf16 rows; MODE 1 -> classifier.
// ---------------------------------------------------------------------------
template<int MODE>
__global__ __launch_bounds__(256) void aggregate(
    const int* __restrict__ offs, const int2* __restrict__ csr2,
    const u32* __restrict__ hb,
    const float* __restrict__ si, const float* __restrict__ sjv,
    const float* __restrict__ P,
    u32* __restrict__ houtb, void* __restrict__ outp,
    const int* __restrict__ flag, int n)
{
    __shared__ int2 cache[4][CAP];
    const int wave = threadIdx.x >> 6, lane = threadIdx.x & 63;
    const int node = blockIdx.x * 4 + wave;
    const bool active = node < n;
    int beg = 0, end = 0;
    if (active) { beg = offs[node]; end = offs[node + 1]; }
    const int deg = end - beg;
    int2* cw = cache[wave];
    const float sii = active ? si[node] : 0.f;

    auto ealpha = [&](int idx) -> int2 {
        int2 st = csr2[beg + idx];
        float a = sii + sjv[st.x] + __int_as_float(st.y);
        a = (a > 0.f) ? a : 0.01f * a;
        return make_int2(st.x, __float_as_int(a));
    };

    // phase A: alpha once per edge, fill LDS cache, wave-max
    float m = -3.4e38f;
    for (int idx = lane; idx < deg; idx += 64) {
        int2 sa = ealpha(idx);
        if (idx < CAP) cw[idx] = sa;
        m = fmaxf(m, __int_as_float(sa.y));
    }
    #pragma unroll
    for (int o = 32; o > 0; o >>= 1) m = fmaxf(m, __shfl_xor(m, o));
    __syncthreads();

    // denominator; overwrite cache with e = exp(alpha - m)
    float ssum = 0.f;
    for (int idx = lane; idx < deg; idx += 64) {
        float a = (idx < CAP) ? __int_as_float(cw[idx].y)
                              : __int_as_float(ealpha(idx).y);
        float e = __expf(a - m);
        if (idx < CAP) cw[idx].y = __float_as_int(e);
        ssum += e;
    }
    #pragma unroll
    for (int o = 32; o > 0; o >>= 1) ssum += __shfl_xor(ssum, o);

    // phase B: half-wave per edge; lane covers features 2*fl, 2*fl+1
    const int half = lane >> 5;
    const int fl = lane & 31;
    float ax = 0.f, ay = 0.f;
    int j0 = 0;
    if (deg <= CAP) {
        for (; j0 + 8 <= deg; j0 += 8) {
            int2 s0 = cw[j0 + 0 + half];
            int2 s1 = cw[j0 + 2 + half];
            int2 s2 = cw[j0 + 4 + half];
            int2 s3 = cw[j0 + 6 + half];
            u32 p0 = hb[(size_t)s0.x * 32 + fl];
            u32 p1 = hb[(size_t)s1.x * 32 + fl];
            u32 p2 = hb[(size_t)s2.x * 32 + fl];
            u32 p3 = hb[(size_t)s3.x * 32 + fl];
            float e0 = __int_as_float(s0.y);
            float e1 = __int_as_float(s1.y);
            float e2 = __int_as_float(s2.y);
            float e3 = __int_as_float(s3.y);
            ax = fmaf(e0, bf2f((u16)(p0 & 0xffffu)), ax);
            ay = fmaf(e0, bf2f((u16)(p0 >> 16)), ay);
            ax = fmaf(e1, bf2f((u16)(p1 & 0xffffu)), ax);
            ay = fmaf(e1, bf2f((u16)(p1 >> 16)), ay);
            ax = fmaf(e2, bf2f((u16)(p2 & 0xffffu)), ax);
            ay = fmaf(e2, bf2f((u16)(p2 >> 16)), ay);
            ax = fmaf(e3, bf2f((u16)(p3 & 0xffffu)), ax);
            ay = fmaf(e3, bf2f((u16)(p3 >> 16)), ay);
        }
    }
    for (; j0 < deg; j0 += 2) {
        int j = j0 + half;
        float ex = 0.f;
        int src = 0;
        if (j < deg) {
            if (j < CAP) {
                int2 sa = cw[j];
                src = sa.x; ex = __int_as_float(sa.y);
            } else {
                int2 sa = ealpha(j);
                src = sa.x; ex = __expf(__int_as_float(sa.y) - m);
            }
        }
        u32 pk = hb[(size_t)src * 32 + fl];
        ax = fmaf(ex, bf2f((u16)(pk & 0xffffu)), ax);
        ay = fmaf(ex, bf2f((u16)(pk >> 16)), ay);
    }
    ax += __shfl_xor(ax, 32);
    ay += __shfl_xor(ay, 32);

    if (!active) return;
    float inv = 1.0f / (ssum + 1e-16f);

    if (MODE == 0) {
        if (lane < 32) {
            float r0 = fmaxf(ax * inv, 0.f);
            float r1 = fmaxf(ay * inv, 0.f);
            houtb[(size_t)node * 32 + fl] = (u32)f2bf(r0) | ((u32)f2bf(r1) << 16);
        }
    } else {
        float r0 = ax * inv, r1 = ay * inv;
        float l0 = r0 * P[P_CLSW + 4 * fl]     + r1 * P[P_CLSW + 4 * fl + 2];
        float l1 = r0 * P[P_CLSW + 4 * fl + 1] + r1 * P[P_CLSW + 4 * fl + 3];
        #pragma unroll
        for (int o = 16; o > 0; o >>= 1) {
            l0 += __shfl_xor(l0, o);
            l1 += __shfl_xor(l1, o);
        }
        if (lane == 0) {
            l0 += P[P_CLSB];
            l1 += P[P_CLSB + 1];
            if (flag[0]) {
                ((float2*)outp)[node] = make_float2(l0, l1);
            } else {
                ((u32*)outp)[node] = (u32)f2bf(l0) | ((u32)f2bf(l1) << 16);
            }
        }
    }
}

// ---------------------------------------------------------------------------
extern "C" void kernel_launch(void* const* d_in, const int* in_sizes, int n_in,
                              void* d_out, int out_size, void* d_ws, size_t ws_size,
                              hipStream_t stream)
{
    const void* x    = d_in[0];
    const int*  ei   = (const int*)d_in[1];
    const void* et   = d_in[2];
    const void* l1w  = d_in[3];
    const void* l1b  = d_in[4];
    const void* a1w  = d_in[5];
    const void* a1b  = d_in[6];
    const void* t1w  = d_in[7];
    const void* t1b  = d_in[8];
    const void* l2w  = d_in[9];
    const void* l2b  = d_in[10];
    const void* a2w  = d_in[11];
    const void* a2b  = d_in[12];
    const void* t2w  = d_in[13];
    const void* t2b  = d_in[14];
    const void* clsw = d_in[15];
    const void* clsb = d_in[16];

    const int N = in_sizes[0] / 128;
    const int E = in_sizes[2];
    const int nchunks = (E + CH - 1) / CH;   // 391 (<= 512 assumed)
    const int nbkt = (N + 511) >> 9;         // buckets actually used

    char* ws = (char*)d_ws;
    size_t off = 0;
    auto A = [&](size_t bytes) -> char* {
        char* p = ws + off;
        off = (off + bytes + 255) & ~(size_t)255;
        return p;
    };
    int*   flag        = (int*)A(256);
    float* P           = (float*)A(P_TOT * 4);
    u32*   h1b         = (u32*)A((size_t)N * 32 * 4);  // bf16 h1; reused as h2
    float* si1         = (float*)A((size_t)N * 4);
    float* sj1         = (float*)A((size_t)N * 4);
    float* si2         = (float*)A((size_t)N * 4);
    float* sj2         = (float*)A((size_t)N * 4);
    int*   chunkhist   = (int*)A((size_t)nchunks * NCHB * 4);
    int*   buckettot   = (int*)A(NCHB * 4);
    int*   bucketstart = (int*)A((size_t)(NCHB + 1) * 4);
    int*   offs        = (int*)A((size_t)(N + 1) * 4);
    int2*  csrA        = (int2*)A((size_t)E * 8);
    int2*  csrB        = (int2*)A((size_t)E * 8);
    char*  unionr      = A((size_t)E * 8 < (size_t)N * 32 * 4
                           ? (size_t)N * 32 * 4 : (size_t)E * 8);
    int2*  staging     = (int2*)unionr;    // sort phase
    u32*   hagb        = (u32*)unionr;     // agg0 bf16 output (after bin)
    (void)ws_size; (void)n_in; (void)out_size;

    detect_dtype<<<1, 256, 0, stream>>>((const u32*)x, 4096, flag);

    prep_params<<<32, 256, 0, stream>>>(l1w, l1b, a1w, a1b, t1w, t1b,
                                        l2w, l2b, a2w, a2b, t2w, t2b,
                                        clsw, clsb, flag, P);

    node_gemm<128, 0><<<(N + 63) / 64, 256, 0, stream>>>(
        x, P, P_W1, P_B1, P_A1W, flag, h1b, si1, sj1, N);

    count_chunks<<<nchunks, 256, 0, stream>>>(ei + E, chunkhist, E);

    scan_chunks<<<NCHB, 256, 0, stream>>>(chunkhist, buckettot, nchunks);

    bucket_start_scan<<<1, 256, 0, stream>>>(buckettot, bucketstart, offs, N);

    place_chunks<<<nchunks, 256, 0, stream>>>(ei, et, flag, chunkhist,
                                              bucketstart, staging, E);

    bin_edges<<<nbkt, 256, 0, stream>>>(staging, bucketstart, P, offs,
                                        csrA, csrB, N);

    aggregate<0><<<(N + 3) / 4, 256, 0, stream>>>(
        offs, csrA, h1b, si1, sj1, P, hagb, nullptr, flag, N);

    node_gemm<64, 2><<<(N + 63) / 64, 256, 0, stream>>>(
        hagb, P, P_W2, P_B2, P_A2W, flag, h1b, si2, sj2, N);

    aggregate<1><<<(N + 3) / 4, 256, 0, stream>>>(
        offs, csrB, h1b, si2, sj2, P, nullptr, d_out, flag, N);
}

// Round 11
// 361.844 us; speedup vs baseline: 1.0428x; 1.0428x over previous
//
#include <hip/hip_runtime.h>

typedef unsigned short u16;
typedef unsigned int u32;

__device__ __forceinline__ float bf2f(u16 u) {
    return __uint_as_float(((u32)u) << 16);
}
__device__ __forceinline__ u16 f2bf(float f) {
    u32 u = __float_as_uint(f);
    u32 r = (u + 0x7fffu + ((u >> 16) & 1u)) >> 16;
    return (u16)r;
}
__device__ __forceinline__ float ldf(const void* p, int i, int isf32) {
    return isf32 ? ((const float*)p)[i] : bf2f(((const u16*)p)[i]);
}

// ---- canonical f32 param block offsets (in floats) ----
#define P_W1   0        // 128x64
#define P_W2   8192     // 64x64
#define P_B1   12288    // 64
#define P_B2   12352    // 64
#define P_A1W  12416    // 144
#define P_A1B  12560    // 1
#define P_T1W  12561    // 16
#define P_T1B  12577    // 16
#define P_A2W  12593    // 144
#define P_A2B  12737    // 1
#define P_T2W  12738    // 16
#define P_T2B  12754    // 16
#define P_CLSW 12770    // 128 (64x2)
#define P_CLSB 12898    // 2
#define P_TOT  12900

#define CH   4096       // edges per sort chunk
#define NCHB 256        // padded bucket count; bucket = dst>>9 (<=195)
#define CAP  512        // aggregate per-node LDS cache

// ---------------------------------------------------------------------------
// Detect f32 vs bf16 storage of float tensors (round-1 notes).
// ---------------------------------------------------------------------------
__global__ __launch_bounds__(256) void detect_dtype(
    const u32* __restrict__ xw, int nwords, int* __restrict__ flag)
{
    __shared__ int sbad;
    if (threadIdx.x == 0) sbad = 0;
    __syncthreads();
    int bad = 0;
    for (int i = threadIdx.x; i < nwords; i += 256) {
        u32 w = xw[i];
        int ea = (w >> 7) & 0xff;
        if (ea >= 0xF0) bad = 1;
    }
    if (bad) sbad = 1;
    __syncthreads();
    if (threadIdx.x == 0) flag[0] = sbad;
}

// ---------------------------------------------------------------------------
// Convert all small parameter tensors into one f32 param block.
// ---------------------------------------------------------------------------
__global__ __launch_bounds__(256) void prep_params(
    const void* l1w, const void* l1b, const void* a1w, const void* a1b,
    const void* t1w, const void* t1b, const void* l2w, const void* l2b,
    const void* a2w, const void* a2b, const void* t2w, const void* t2b,
    const void* clsw, const void* clsb,
    const int* __restrict__ flag, float* __restrict__ P)
{
    const int f = flag[0];
    const int t = blockIdx.x * 256 + threadIdx.x;
    const int stride = gridDim.x * 256;
#define SEG(src, off, cnt) for (int i = t; i < (cnt); i += stride) P[(off) + i] = ldf(src, i, f)
    SEG(l1w, P_W1, 8192);
    SEG(l2w, P_W2, 4096);
    SEG(l1b, P_B1, 64);
    SEG(l2b, P_B2, 64);
    SEG(a1w, P_A1W, 144);
    SEG(a1b, P_A1B, 1);
    SEG(t1w, P_T1W, 16);
    SEG(t1b, P_T1B, 16);
    SEG(a2w, P_A2W, 144);
    SEG(a2b, P_A2B, 1);
    SEG(t2w, P_T2W, 16);
    SEG(t2b, P_T2B, 16);
    SEG(clsw, P_CLSW, 128);
    SEG(clsb, P_CLSB, 2);
#undef SEG
}

// ---------------------------------------------------------------------------
// Node transform as tiled GEMM: h = x @ W + b packed bf16; fused si/sj.
// XMODE: 0 = runtime flag (f32/bf16), 1 = f32 input, 2 = bf16 input.
// ---------------------------------------------------------------------------
template<int K, int XMODE>
__global__ __launch_bounds__(256) void node_gemm(
    const void* __restrict__ xin, const float* __restrict__ P,
    int WOFF, int BOFF, int AOFF, const int* __restrict__ flag,
    u32* __restrict__ houtb, float* __restrict__ si, float* __restrict__ sj,
    int nnodes)
{
    __shared__ float Ws[K * 64];
    __shared__ float As[32][66];
    const int t = threadIdx.x;
    const int tx = t & 15;
    const int ty = t >> 4;
    const int base = blockIdx.x * 64;
    const bool xf32 = (XMODE == 0) ? (flag[0] != 0) : (XMODE == 1);

    for (int i = t * 4; i < K * 64; i += 1024)
        *(float4*)&Ws[i] = *(const float4*)&P[WOFF + i];

    float acc[4][4];
    #pragma unroll
    for (int r = 0; r < 4; ++r)
        #pragma unroll
        for (int c = 0; c < 4; ++c) acc[r][c] = 0.f;

    for (int k0 = 0; k0 < K; k0 += 32) {
        __syncthreads();
        if (xf32) {
            #pragma unroll
            for (int it = 0; it < 2; ++it) {
                int idx = t + it * 256;
                int row = idx >> 3, cq = (idx & 7) * 4;
                float4 v = make_float4(0.f, 0.f, 0.f, 0.f);
                if (base + row < nnodes)
                    v = *(const float4*)&((const float*)xin)[(size_t)(base + row) * K + k0 + cq];
                As[cq + 0][row] = v.x; As[cq + 1][row] = v.y;
                As[cq + 2][row] = v.z; As[cq + 3][row] = v.w;
            }
        } else {
            int row = t >> 2, q = (t & 3) * 8;
            uint4 v = make_uint4(0u, 0u, 0u, 0u);
            if (base + row < nnodes)
                v = *(const uint4*)&((const u16*)xin)[(size_t)(base + row) * K + k0 + q];
            As[q + 0][row] = bf2f((u16)(v.x & 0xffffu));
            As[q + 1][row] = bf2f((u16)(v.x >> 16));
            As[q + 2][row] = bf2f((u16)(v.y & 0xffffu));
            As[q + 3][row] = bf2f((u16)(v.y >> 16));
            As[q + 4][row] = bf2f((u16)(v.z & 0xffffu));
            As[q + 5][row] = bf2f((u16)(v.z >> 16));
            As[q + 6][row] = bf2f((u16)(v.w & 0xffffu));
            As[q + 7][row] = bf2f((u16)(v.w >> 16));
        }
        __syncthreads();

        #pragma unroll
        for (int k = 0; k < 32; ++k) {
            float2 a01 = *(float2*)&As[k][ty * 4];
            float2 a23 = *(float2*)&As[k][ty * 4 + 2];
            float4 b = *(float4*)&Ws[(k0 + k) * 64 + tx * 4];
            float a[4] = { a01.x, a01.y, a23.x, a23.y };
            float bb[4] = { b.x, b.y, b.z, b.w };
            #pragma unroll
            for (int r = 0; r < 4; ++r)
                #pragma unroll
                for (int c = 0; c < 4; ++c)
                    acc[r][c] = fmaf(a[r], bb[c], acc[r][c]);
        }
    }

    #pragma unroll
    for (int c = 0; c < 4; ++c) {
        float bc = P[BOFF + tx * 4 + c];
        #pragma unroll
        for (int r = 0; r < 4; ++r) acc[r][c] += bc;
    }

    float vi[4], vj[4];
    #pragma unroll
    for (int r = 0; r < 4; ++r) {
        float a_i = 0.f, a_j = 0.f;
        #pragma unroll
        for (int c = 0; c < 4; ++c) {
            a_i = fmaf(acc[r][c], P[AOFF + tx * 4 + c], a_i);
            a_j = fmaf(acc[r][c], P[AOFF + 64 + tx * 4 + c], a_j);
        }
        vi[r] = a_i; vj[r] = a_j;
    }
    #pragma unroll
    for (int o = 1; o < 16; o <<= 1) {
        #pragma unroll
        for (int r = 0; r < 4; ++r) {
            vi[r] += __shfl_xor(vi[r], o);
            vj[r] += __shfl_xor(vj[r], o);
        }
    }

    #pragma unroll
    for (int r = 0; r < 4; ++r) {
        int node = base + ty * 4 + r;
        if (node < nnodes) {
            u32 w0 = (u32)f2bf(acc[r][0]) | ((u32)f2bf(acc[r][1]) << 16);
            u32 w1 = (u32)f2bf(acc[r][2]) | ((u32)f2bf(acc[r][3]) << 16);
            *(uint2*)&houtb[(size_t)node * 32 + tx * 2] = make_uint2(w0, w1);
            if (tx == 0) { si[node] = vi[r]; sj[node] = vj[r]; }
        }
    }
}

// ---------------------------------------------------------------------------
// Counting sort pass 1: per-chunk bucket histogram (bucket = dst>>9).
// ---------------------------------------------------------------------------
__global__ __launch_bounds__(256) void count_chunks(
    const int* __restrict__ eid, int* __restrict__ chunkhist, int E)
{
    __shared__ int hist[NCHB];
    const int t = threadIdx.x, c = blockIdx.x;
    hist[t] = 0;
    __syncthreads();
    const int base = c * CH;
    #pragma unroll
    for (int i = 0; i < CH / 256; ++i) {
        int e = base + t + i * 256;
        if (e < E) atomicAdd(&hist[eid[e] >> 9], 1);
    }
    __syncthreads();
    chunkhist[c * NCHB + t] = hist[t];
}

// ---------------------------------------------------------------------------
// Scan stage A: one block per bucket; Hillis-Steele over chunk entries.
// ---------------------------------------------------------------------------
__global__ __launch_bounds__(256) void scan_chunks(
    int* __restrict__ chunkhist, int* __restrict__ buckettot, int nchunks)
{
    __shared__ int s[512];
    const int b = blockIdx.x, t = threadIdx.x;
    int v0 = (t < nchunks) ? chunkhist[(size_t)t * NCHB + b] : 0;
    int v1 = (t + 256 < nchunks) ? chunkhist[(size_t)(t + 256) * NCHB + b] : 0;
    s[t] = v0; s[t + 256] = v1;
    __syncthreads();
    for (int off = 1; off < 512; off <<= 1) {
        int x0 = (t >= off) ? s[t - off] : 0;
        int x1 = s[t + 256 - off];
        __syncthreads();
        s[t] += x0; s[t + 256] += x1;
        __syncthreads();
    }
    if (t < nchunks) chunkhist[(size_t)t * NCHB + b] = s[t] - v0;
    if (t + 256 < nchunks) chunkhist[(size_t)(t + 256) * NCHB + b] = s[t + 256] - v1;
    if (t == 255) buckettot[b] = s[511];
}

// ---------------------------------------------------------------------------
// Scan stage B: 1 tiny block. Exclusive scan of bucket totals.
// ---------------------------------------------------------------------------
__global__ __launch_bounds__(256) void bucket_start_scan(
    const int* __restrict__ buckettot, int* __restrict__ bucketstart,
    int* __restrict__ offs, int N)
{
    __shared__ int s[NCHB];
    const int b = threadIdx.x;
    int v = buckettot[b];
    s[b] = v;
    __syncthreads();
    for (int off = 1; off < NCHB; off <<= 1) {
        int x = (b >= off) ? s[b - off] : 0;
        __syncthreads();
        s[b] += x;
        __syncthreads();
    }
    bucketstart[b] = s[b] - v;
    if (b == NCHB - 1) { bucketstart[NCHB] = s[b]; offs[N] = s[b]; }
}

// ---------------------------------------------------------------------------
// Counting sort pass 2: sort each chunk in LDS, coalesced flush to the
// bucket-sorted staging array. Payload (src | ldst<<17, t_bits).
// ---------------------------------------------------------------------------
__global__ __launch_bounds__(256) void place_chunks(
    const int* __restrict__ ei, const void* __restrict__ et,
    const int* __restrict__ flag, const int* __restrict__ chunkhist,
    const int* __restrict__ bucketstart, int2* __restrict__ staging, int E)
{
    __shared__ int2 sorted[CH];            // 32 KB
    __shared__ unsigned char bno[CH];      // 4 KB
    __shared__ int hist[NCHB], lstart[NCHB], cur[NCHB], gb[NCHB];
    const int t = threadIdx.x, c = blockIdx.x;
    const int base = c * CH;
    const int f = flag[0];
    hist[t] = 0;
    gb[t] = bucketstart[t] + chunkhist[c * NCHB + t];
    __syncthreads();
    #pragma unroll
    for (int i = 0; i < CH / 256; ++i) {
        int e = base + t + i * 256;
        if (e < E) atomicAdd(&hist[ei[E + e] >> 9], 1);
    }
    __syncthreads();
    int v = hist[t];
    lstart[t] = v;
    __syncthreads();
    for (int off = 1; off < NCHB; off <<= 1) {
        int x = (t >= off) ? lstart[t - off] : 0;
        __syncthreads();
        lstart[t] += x;
        __syncthreads();
    }
    int ex = lstart[t] - v;   // exclusive local start
    __syncthreads();
    lstart[t] = ex;
    cur[t] = ex;
    __syncthreads();
    #pragma unroll
    for (int i = 0; i < CH / 256; ++i) {
        int e = base + t + i * 256;
        if (e < E) {
            int s_ = ei[e], d = ei[E + e];
            float tt = ldf(et, e, f);
            int b = d >> 9;
            int p = atomicAdd(&cur[b], 1);
            sorted[p] = make_int2(s_ | ((d & 511) << 17), __float_as_int(tt));
            bno[p] = (unsigned char)b;
        }
    }
    __syncthreads();
    const int cnt_tot = min(CH, E - base);
    for (int idx = t; idx < cnt_tot; idx += 256) {
        int b = bno[idx];
        staging[gb[b] + (idx - lstart[b])] = sorted[idx];
    }
}

// ---------------------------------------------------------------------------
// Bin within bucket (round-9 shape, low VGPR): per-node LDS histogram + scan
// -> offs; place (src, t) into node-sorted csrA.
// ---------------------------------------------------------------------------
__global__ __launch_bounds__(256) void bin_edges(
    const int2* __restrict__ staging, const int* __restrict__ bucketstart,
    int* __restrict__ offs, int2* __restrict__ csrA, int N)
{
    __shared__ int cnt[512], loc[512];
    const int b = blockIdx.x, t = threadIdx.x;
    const int beg = bucketstart[b], end = bucketstart[b + 1];
    const int nstart = b << 9;
    cnt[t] = 0; cnt[t + 256] = 0;
    __syncthreads();
    for (int i = beg + t; i < end; i += 256)
        atomicAdd(&cnt[(((u32)staging[i].x) >> 17) & 511], 1);
    __syncthreads();
    int v0 = cnt[t], v1 = cnt[t + 256];
    loc[t] = v0; loc[t + 256] = v1;
    __syncthreads();
    for (int off = 1; off < 512; off <<= 1) {
        int x0 = (t >= off) ? loc[t - off] : 0;
        int x1 = loc[t + 256 - off];
        __syncthreads();
        loc[t] += x0; loc[t + 256] += x1;
        __syncthreads();
    }
    int cur0 = beg + loc[t] - v0;
    int cur1 = beg + loc[t + 256] - v1;
    if (nstart + t < N) offs[nstart + t] = cur0;
    if (nstart + t + 256 < N) offs[nstart + t + 256] = cur1;
    cnt[t] = cur0; cnt[t + 256] = cur1;
    __syncthreads();
    for (int i = beg + t; i < end; i += 256) {
        int2 e = staging[i];
        int slot = atomicAdd(&cnt[(((u32)e.x) >> 17) & 511], 1);
        csrA[slot] = make_int2(e.x & 0x1ffff, e.y);
    }
}

// ---------------------------------------------------------------------------
// Temporal pass: fully-coalesced stream over the node-sorted CSR. Computes
// both layers' sin dots at full 64-lane efficiency: csrA -> (src, td1+b1)
// in place, csrB = (src, td2+b2). Removes all sin from the hot aggregates
// without polluting bin_edges' register budget (round-10 lesson).
// ---------------------------------------------------------------------------
__global__ __launch_bounds__(256) void temporal_pass(
    int2* __restrict__ csrA, int2* __restrict__ csrB,
    const float* __restrict__ P, int E)
{
    int i = blockIdx.x * 256 + threadIdx.x;
    if (i >= E) return;
    int2 e = csrA[i];
    float tt = __int_as_float(e.y);
    float td1 = P[P_A1B], td2 = P[P_A2B];
    #pragma unroll
    for (int k = 0; k < 16; ++k) {
        td1 += __sinf(fmaf(tt, P[P_T1W + k], P[P_T1B + k])) * P[P_A1W + 128 + k];
        td2 += __sinf(fmaf(tt, P[P_T2W + k], P[P_T2B + k])) * P[P_A2W + 128 + k];
    }
    csrA[i] = make_int2(e.x, __float_as_int(td1));
    csrB[i] = make_int2(e.x, __float_as_int(td2));
}

// ---------------------------------------------------------------------------
// Aggregate: wave per node, SINGLE alpha pass (no max subtraction: alpha =
// leaky(si+sj+tdb) is bounded by construction; clamp at 80 for safety —
// softmax ratio is mathematically unchanged). Cache holds (src, e). Phase B:
// half-wave per edge, 4 row-loads in flight, 32-bit indexing.
// ---------------------------------------------------------------------------
template<int MODE>
__global__ __launch_bounds__(256) void aggregate(
    const int* __restrict__ offs, const int2* __restrict__ csr2,
    const u32* __restrict__ hb,
    const float* __restrict__ si, const float* __restrict__ sjv,
    const float* __restrict__ P,
    u32* __restrict__ houtb, void* __restrict__ outp,
    const int* __restrict__ flag, int n)
{
    __shared__ int2 cache[4][CAP];
    const int wave = threadIdx.x >> 6, lane = threadIdx.x & 63;
    const int node = blockIdx.x * 4 + wave;
    const bool active = node < n;
    int beg = 0, end = 0;
    if (active) { beg = offs[node]; end = offs[node + 1]; }
    const int deg = end - beg;
    int2* cw = cache[wave];
    const float sii = active ? si[node] : 0.f;

    // single pass: alpha -> e = exp(alpha), LDS cache, ssum
    float ssum = 0.f;
    for (int idx = lane; idx < deg; idx += 64) {
        int2 st = csr2[beg + idx];
        float a = sii + sjv[st.x] + __int_as_float(st.y);
        a = (a > 0.f) ? a : 0.01f * a;
        float e = __expf(fminf(a, 80.f));
        if (idx < CAP) cw[idx] = make_int2(st.x, __float_as_int(e));
        ssum += e;
    }
    #pragma unroll
    for (int o = 32; o > 0; o >>= 1) ssum += __shfl_xor(ssum, o);
    __syncthreads();

    // phase B: half-wave per edge; lane covers features 2*fl, 2*fl+1
    const int half = lane >> 5;
    const int fl = lane & 31;
    float ax = 0.f, ay = 0.f;
    int j0 = 0;
    if (deg <= CAP) {
        for (; j0 + 8 <= deg; j0 += 8) {
            int2 s0 = cw[j0 + 0 + half];
            int2 s1 = cw[j0 + 2 + half];
            int2 s2 = cw[j0 + 4 + half];
            int2 s3 = cw[j0 + 6 + half];
            u32 p0 = hb[s0.x * 32 + fl];
            u32 p1 = hb[s1.x * 32 + fl];
            u32 p2 = hb[s2.x * 32 + fl];
            u32 p3 = hb[s3.x * 32 + fl];
            float e0 = __int_as_float(s0.y);
            float e1 = __int_as_float(s1.y);
            float e2 = __int_as_float(s2.y);
            float e3 = __int_as_float(s3.y);
            ax = fmaf(e0, __uint_as_float(p0 << 16), ax);
            ay = fmaf(e0, __uint_as_float(p0 & 0xffff0000u), ay);
            ax = fmaf(e1, __uint_as_float(p1 << 16), ax);
            ay = fmaf(e1, __uint_as_float(p1 & 0xffff0000u), ay);
            ax = fmaf(e2, __uint_as_float(p2 << 16), ax);
            ay = fmaf(e2, __uint_as_float(p2 & 0xffff0000u), ay);
            ax = fmaf(e3, __uint_as_float(p3 << 16), ax);
            ay = fmaf(e3, __uint_as_float(p3 & 0xffff0000u), ay);
        }
    }
    for (; j0 < deg; j0 += 2) {
        int j = j0 + half;
        float ex = 0.f;
        int src = 0;
        if (j < deg) {
            if (j < CAP) {
                int2 sa = cw[j];
                src = sa.x; ex = __int_as_float(sa.y);
            } else {
                int2 st = csr2[beg + j];
                float a = sii + sjv[st.x] + __int_as_float(st.y);
                a = (a > 0.f) ? a : 0.01f * a;
                src = st.x; ex = __expf(fminf(a, 80.f));
            }
        }
        u32 pk = hb[src * 32 + fl];
        ax = fmaf(ex, __uint_as_float(pk << 16), ax);
        ay = fmaf(ex, __uint_as_float(pk & 0xffff0000u), ay);
    }
    ax += __shfl_xor(ax, 32);
    ay += __shfl_xor(ay, 32);

    if (!active) return;
    float inv = 1.0f / (ssum + 1e-16f);

    if (MODE == 0) {
        if (lane < 32) {
            float r0 = fmaxf(ax * inv, 0.f);
            float r1 = fmaxf(ay * inv, 0.f);
            houtb[(size_t)node * 32 + fl] = (u32)f2bf(r0) | ((u32)f2bf(r1) << 16);
        }
    } else {
        float r0 = ax * inv, r1 = ay * inv;
        float l0 = r0 * P[P_CLSW + 4 * fl]     + r1 * P[P_CLSW + 4 * fl + 2];
        float l1 = r0 * P[P_CLSW + 4 * fl + 1] + r1 * P[P_CLSW + 4 * fl + 3];
        #pragma unroll
        for (int o = 16; o > 0; o >>= 1) {
            l0 += __shfl_xor(l0, o);
            l1 += __shfl_xor(l1, o);
        }
        if (lane == 0) {
            l0 += P[P_CLSB];
            l1 += P[P_CLSB + 1];
            if (flag[0]) {
                ((float2*)outp)[node] = make_float2(l0, l1);
            } else {
                ((u32*)outp)[node] = (u32)f2bf(l0) | ((u32)f2bf(l1) << 16);
            }
        }
    }
}

// ---------------------------------------------------------------------------
extern "C" void kernel_launch(void* const* d_in, const int* in_sizes, int n_in,
                              void* d_out, int out_size, void* d_ws, size_t ws_size,
                              hipStream_t stream)
{
    const void* x    = d_in[0];
    const int*  ei   = (const int*)d_in[1];
    const void* et   = d_in[2];
    const void* l1w  = d_in[3];
    const void* l1b  = d_in[4];
    const void* a1w  = d_in[5];
    const void* a1b  = d_in[6];
    const void* t1w  = d_in[7];
    const void* t1b  = d_in[8];
    const void* l2w  = d_in[9];
    const void* l2b  = d_in[10];
    const void* a2w  = d_in[11];
    const void* a2b  = d_in[12];
    const void* t2w  = d_in[13];
    const void* t2b  = d_in[14];
    const void* clsw = d_in[15];
    const void* clsb = d_in[16];

    const int N = in_sizes[0] / 128;
    const int E = in_sizes[2];
    const int nchunks = (E + CH - 1) / CH;   // 391 (<= 512 assumed)
    const int nbkt = (N + 511) >> 9;         // buckets actually used

    char* ws = (char*)d_ws;
    size_t off = 0;
    auto A = [&](size_t bytes) -> char* {
        char* p = ws + off;
        off = (off + bytes + 255) & ~(size_t)255;
        return p;
    };
    int*   flag        = (int*)A(256);
    float* P           = (float*)A(P_TOT * 4);
    u32*   h1b         = (u32*)A((size_t)N * 32 * 4);  // bf16 h1; reused as h2
    float* si1         = (float*)A((size_t)N * 4);
    float* sj1         = (float*)A((size_t)N * 4);
    float* si2         = (float*)A((size_t)N * 4);
    float* sj2         = (float*)A((size_t)N * 4);
    int*   chunkhist   = (int*)A((size_t)nchunks * NCHB * 4);
    int*   buckettot   = (int*)A(NCHB * 4);
    int*   bucketstart = (int*)A((size_t)(NCHB + 1) * 4);
    int*   offs        = (int*)A((size_t)(N + 1) * 4);
    int2*  csrA        = (int2*)A((size_t)E * 8);
    int2*  csrB        = (int2*)A((size_t)E * 8);
    char*  unionr      = A((size_t)E * 8 < (size_t)N * 32 * 4
                           ? (size_t)N * 32 * 4 : (size_t)E * 8);
    int2*  staging     = (int2*)unionr;    // sort phase
    u32*   hagb        = (u32*)unionr;     // agg0 bf16 output (after bin)
    (void)ws_size; (void)n_in; (void)out_size;

    detect_dtype<<<1, 256, 0, stream>>>((const u32*)x, 4096, flag);

    prep_params<<<32, 256, 0, stream>>>(l1w, l1b, a1w, a1b, t1w, t1b,
                                        l2w, l2b, a2w, a2b, t2w, t2b,
                                        clsw, clsb, flag, P);

    node_gemm<128, 0><<<(N + 63) / 64, 256, 0, stream>>>(
        x, P, P_W1, P_B1, P_A1W, flag, h1b, si1, sj1, N);

    count_chunks<<<nchunks, 256, 0, stream>>>(ei + E, chunkhist, E);

    scan_chunks<<<NCHB, 256, 0, stream>>>(chunkhist, buckettot, nchunks);

    bucket_start_scan<<<1, 256, 0, stream>>>(buckettot, bucketstart, offs, N);

    place_chunks<<<nchunks, 256, 0, stream>>>(ei, et, flag, chunkhist,
                                              bucketstart, staging, E);

    bin_edges<<<nbkt, 256, 0, stream>>>(staging, bucketstart, offs, csrA, N);

    temporal_pass<<<(E + 255) / 256, 256, 0, stream>>>(csrA, csrB, P, E);

    aggregate<0><<<(N + 3) / 4, 256, 0, stream>>>(
        offs, csrA, h1b, si1, sj1, P, hagb, nullptr, flag, N);

    node_gemm<64, 2><<<(N + 63) / 64, 256, 0, stream>>>(
        hagb, P, P_W2, P_B2, P_A2W, flag, h1b, si2, sj2, N);

    aggregate<1><<<(N + 3) / 4, 256, 0, stream>>>(
        offs, csrB, h1b, si2, sj2, P, nullptr, d_out, flag, N);
}

// Round 12
// 331.441 us; speedup vs baseline: 1.1384x; 1.0917x over previous
//
#include <hip/hip_runtime.h>

typedef unsigned short u16;
typedef unsigned int u32;

__device__ __forceinline__ float bf2f(u16 u) {
    return __uint_as_float(((u32)u) << 16);
}
__device__ __forceinline__ u16 f2bf(float f) {
    u32 u = __float_as_uint(f);
    u32 r = (u + 0x7fffu + ((u >> 16) & 1u)) >> 16;
    return (u16)r;
}
__device__ __forceinline__ float ldf(const void* p, int i, int isf32) {
    return isf32 ? ((const float*)p)[i] : bf2f(((const u16*)p)[i]);
}

// ---- canonical f32 param block offsets (in floats) ----
#define P_W1   0        // 128x64
#define P_W2   8192     // 64x64
#define P_B1   12288    // 64
#define P_B2   12352    // 64
#define P_A1W  12416    // 144
#define P_A1B  12560    // 1
#define P_T1W  12561    // 16
#define P_T1B  12577    // 16
#define P_A2W  12593    // 144
#define P_A2B  12737    // 1
#define P_T2W  12738    // 16
#define P_T2B  12754    // 16
#define P_CLSW 12770    // 128 (64x2)
#define P_CLSB 12898    // 2
#define P_TOT  12900

#define CH   4096       // edges per sort chunk
#define NCHB 256        // padded bucket count; bucket = dst>>9 (<=195)
#define CAP  128        // aggregate per-node LDS cache (max observed deg ~50)

// ---------------------------------------------------------------------------
// Detect f32 vs bf16 storage of float tensors (round-1 notes).
// ---------------------------------------------------------------------------
__global__ __launch_bounds__(256) void detect_dtype(
    const u32* __restrict__ xw, int nwords, int* __restrict__ flag)
{
    __shared__ int sbad;
    if (threadIdx.x == 0) sbad = 0;
    __syncthreads();
    int bad = 0;
    for (int i = threadIdx.x; i < nwords; i += 256) {
        u32 w = xw[i];
        int ea = (w >> 7) & 0xff;
        if (ea >= 0xF0) bad = 1;
    }
    if (bad) sbad = 1;
    __syncthreads();
    if (threadIdx.x == 0) flag[0] = sbad;
}

// ---------------------------------------------------------------------------
// Convert all small parameter tensors into one f32 param block.
// ---------------------------------------------------------------------------
__global__ __launch_bounds__(256) void prep_params(
    const void* l1w, const void* l1b, const void* a1w, const void* a1b,
    const void* t1w, const void* t1b, const void* l2w, const void* l2b,
    const void* a2w, const void* a2b, const void* t2w, const void* t2b,
    const void* clsw, const void* clsb,
    const int* __restrict__ flag, float* __restrict__ P)
{
    const int f = flag[0];
    const int t = blockIdx.x * 256 + threadIdx.x;
    const int stride = gridDim.x * 256;
#define SEG(src, off, cnt) for (int i = t; i < (cnt); i += stride) P[(off) + i] = ldf(src, i, f)
    SEG(l1w, P_W1, 8192);
    SEG(l2w, P_W2, 4096);
    SEG(l1b, P_B1, 64);
    SEG(l2b, P_B2, 64);
    SEG(a1w, P_A1W, 144);
    SEG(a1b, P_A1B, 1);
    SEG(t1w, P_T1W, 16);
    SEG(t1b, P_T1B, 16);
    SEG(a2w, P_A2W, 144);
    SEG(a2b, P_A2B, 1);
    SEG(t2w, P_T2W, 16);
    SEG(t2b, P_T2B, 16);
    SEG(clsw, P_CLSW, 128);
    SEG(clsb, P_CLSB, 2);
#undef SEG
}

// ---------------------------------------------------------------------------
// Node transform as tiled GEMM: h = x @ W + b packed bf16; fused si/sj.
// XMODE: 0 = runtime flag (f32/bf16), 1 = f32 input, 2 = bf16 input.
// ---------------------------------------------------------------------------
template<int K, int XMODE>
__global__ __launch_bounds__(256) void node_gemm(
    const void* __restrict__ xin, const float* __restrict__ P,
    int WOFF, int BOFF, int AOFF, const int* __restrict__ flag,
    u32* __restrict__ houtb, float* __restrict__ si, float* __restrict__ sj,
    int nnodes)
{
    __shared__ float Ws[K * 64];
    __shared__ float As[32][66];
    const int t = threadIdx.x;
    const int tx = t & 15;
    const int ty = t >> 4;
    const int base = blockIdx.x * 64;
    const bool xf32 = (XMODE == 0) ? (flag[0] != 0) : (XMODE == 1);

    for (int i = t * 4; i < K * 64; i += 1024)
        *(float4*)&Ws[i] = *(const float4*)&P[WOFF + i];

    float acc[4][4];
    #pragma unroll
    for (int r = 0; r < 4; ++r)
        #pragma unroll
        for (int c = 0; c < 4; ++c) acc[r][c] = 0.f;

    for (int k0 = 0; k0 < K; k0 += 32) {
        __syncthreads();
        if (xf32) {
            #pragma unroll
            for (int it = 0; it < 2; ++it) {
                int idx = t + it * 256;
                int row = idx >> 3, cq = (idx & 7) * 4;
                float4 v = make_float4(0.f, 0.f, 0.f, 0.f);
                if (base + row < nnodes)
                    v = *(const float4*)&((const float*)xin)[(size_t)(base + row) * K + k0 + cq];
                As[cq + 0][row] = v.x; As[cq + 1][row] = v.y;
                As[cq + 2][row] = v.z; As[cq + 3][row] = v.w;
            }
        } else {
            int row = t >> 2, q = (t & 3) * 8;
            uint4 v = make_uint4(0u, 0u, 0u, 0u);
            if (base + row < nnodes)
                v = *(const uint4*)&((const u16*)xin)[(size_t)(base + row) * K + k0 + q];
            As[q + 0][row] = bf2f((u16)(v.x & 0xffffu));
            As[q + 1][row] = bf2f((u16)(v.x >> 16));
            As[q + 2][row] = bf2f((u16)(v.y & 0xffffu));
            As[q + 3][row] = bf2f((u16)(v.y >> 16));
            As[q + 4][row] = bf2f((u16)(v.z & 0xffffu));
            As[q + 5][row] = bf2f((u16)(v.z >> 16));
            As[q + 6][row] = bf2f((u16)(v.w & 0xffffu));
            As[q + 7][row] = bf2f((u16)(v.w >> 16));
        }
        __syncthreads();

        #pragma unroll
        for (int k = 0; k < 32; ++k) {
            float2 a01 = *(float2*)&As[k][ty * 4];
            float2 a23 = *(float2*)&As[k][ty * 4 + 2];
            float4 b = *(float4*)&Ws[(k0 + k) * 64 + tx * 4];
            float a[4] = { a01.x, a01.y, a23.x, a23.y };
            float bb[4] = { b.x, b.y, b.z, b.w };
            #pragma unroll
            for (int r = 0; r < 4; ++r)
                #pragma unroll
                for (int c = 0; c < 4; ++c)
                    acc[r][c] = fmaf(a[r], bb[c], acc[r][c]);
        }
    }

    #pragma unroll
    for (int c = 0; c < 4; ++c) {
        float bc = P[BOFF + tx * 4 + c];
        #pragma unroll
        for (int r = 0; r < 4; ++r) acc[r][c] += bc;
    }

    float vi[4], vj[4];
    #pragma unroll
    for (int r = 0; r < 4; ++r) {
        float a_i = 0.f, a_j = 0.f;
        #pragma unroll
        for (int c = 0; c < 4; ++c) {
            a_i = fmaf(acc[r][c], P[AOFF + tx * 4 + c], a_i);
            a_j = fmaf(acc[r][c], P[AOFF + 64 + tx * 4 + c], a_j);
        }
        vi[r] = a_i; vj[r] = a_j;
    }
    #pragma unroll
    for (int o = 1; o < 16; o <<= 1) {
        #pragma unroll
        for (int r = 0; r < 4; ++r) {
            vi[r] += __shfl_xor(vi[r], o);
            vj[r] += __shfl_xor(vj[r], o);
        }
    }

    #pragma unroll
    for (int r = 0; r < 4; ++r) {
        int node = base + ty * 4 + r;
        if (node < nnodes) {
            u32 w0 = (u32)f2bf(acc[r][0]) | ((u32)f2bf(acc[r][1]) << 16);
            u32 w1 = (u32)f2bf(acc[r][2]) | ((u32)f2bf(acc[r][3]) << 16);
            *(uint2*)&houtb[(size_t)node * 32 + tx * 2] = make_uint2(w0, w1);
            if (tx == 0) { si[node] = vi[r]; sj[node] = vj[r]; }
        }
    }
}

// ---------------------------------------------------------------------------
// Counting sort pass 1: per-chunk bucket histogram (bucket = dst>>9).
// ---------------------------------------------------------------------------
__global__ __launch_bounds__(256) void count_chunks(
    const int* __restrict__ eid, int* __restrict__ chunkhist, int E)
{
    __shared__ int hist[NCHB];
    const int t = threadIdx.x, c = blockIdx.x;
    hist[t] = 0;
    __syncthreads();
    const int base = c * CH;
    #pragma unroll
    for (int i = 0; i < CH / 256; ++i) {
        int e = base + t + i * 256;
        if (e < E) atomicAdd(&hist[eid[e] >> 9], 1);
    }
    __syncthreads();
    chunkhist[c * NCHB + t] = hist[t];
}

// ---------------------------------------------------------------------------
// Scan stage A: one block per bucket; Hillis-Steele over chunk entries.
// ---------------------------------------------------------------------------
__global__ __launch_bounds__(256) void scan_chunks(
    int* __restrict__ chunkhist, int* __restrict__ buckettot, int nchunks)
{
    __shared__ int s[512];
    const int b = blockIdx.x, t = threadIdx.x;
    int v0 = (t < nchunks) ? chunkhist[(size_t)t * NCHB + b] : 0;
    int v1 = (t + 256 < nchunks) ? chunkhist[(size_t)(t + 256) * NCHB + b] : 0;
    s[t] = v0; s[t + 256] = v1;
    __syncthreads();
    for (int off = 1; off < 512; off <<= 1) {
        int x0 = (t >= off) ? s[t - off] : 0;
        int x1 = s[t + 256 - off];
        __syncthreads();
        s[t] += x0; s[t + 256] += x1;
        __syncthreads();
    }
    if (t < nchunks) chunkhist[(size_t)t * NCHB + b] = s[t] - v0;
    if (t + 256 < nchunks) chunkhist[(size_t)(t + 256) * NCHB + b] = s[t + 256] - v1;
    if (t == 255) buckettot[b] = s[511];
}

// ---------------------------------------------------------------------------
// Scan stage B: 1 tiny block. Exclusive scan of bucket totals.
// ---------------------------------------------------------------------------
__global__ __launch_bounds__(256) void bucket_start_scan(
    const int* __restrict__ buckettot, int* __restrict__ bucketstart,
    int* __restrict__ offs, int N)
{
    __shared__ int s[NCHB];
    const int b = threadIdx.x;
    int v = buckettot[b];
    s[b] = v;
    __syncthreads();
    for (int off = 1; off < NCHB; off <<= 1) {
        int x = (b >= off) ? s[b - off] : 0;
        __syncthreads();
        s[b] += x;
        __syncthreads();
    }
    bucketstart[b] = s[b] - v;
    if (b == NCHB - 1) { bucketstart[NCHB] = s[b]; offs[N] = s[b]; }
}

// ---------------------------------------------------------------------------
// Counting sort pass 2: sort each chunk in LDS, coalesced flush to the
// bucket-sorted staging array. Payload (src | ldst<<17, t_bits).
// ---------------------------------------------------------------------------
__global__ __launch_bounds__(256) void place_chunks(
    const int* __restrict__ ei, const void* __restrict__ et,
    const int* __restrict__ flag, const int* __restrict__ chunkhist,
    const int* __restrict__ bucketstart, int2* __restrict__ staging, int E)
{
    __shared__ int2 sorted[CH];            // 32 KB
    __shared__ unsigned char bno[CH];      // 4 KB
    __shared__ int hist[NCHB], lstart[NCHB], cur[NCHB], gb[NCHB];
    const int t = threadIdx.x, c = blockIdx.x;
    const int base = c * CH;
    const int f = flag[0];
    hist[t] = 0;
    gb[t] = bucketstart[t] + chunkhist[c * NCHB + t];
    __syncthreads();
    #pragma unroll
    for (int i = 0; i < CH / 256; ++i) {
        int e = base + t + i * 256;
        if (e < E) atomicAdd(&hist[ei[E + e] >> 9], 1);
    }
    __syncthreads();
    int v = hist[t];
    lstart[t] = v;
    __syncthreads();
    for (int off = 1; off < NCHB; off <<= 1) {
        int x = (t >= off) ? lstart[t - off] : 0;
        __syncthreads();
        lstart[t] += x;
        __syncthreads();
    }
    int ex = lstart[t] - v;   // exclusive local start
    __syncthreads();
    lstart[t] = ex;
    cur[t] = ex;
    __syncthreads();
    #pragma unroll
    for (int i = 0; i < CH / 256; ++i) {
        int e = base + t + i * 256;
        if (e < E) {
            int s_ = ei[e], d = ei[E + e];
            float tt = ldf(et, e, f);
            int b = d >> 9;
            int p = atomicAdd(&cur[b], 1);
            sorted[p] = make_int2(s_ | ((d & 511) << 17), __float_as_int(tt));
            bno[p] = (unsigned char)b;
        }
    }
    __syncthreads();
    const int cnt_tot = min(CH, E - base);
    for (int idx = t; idx < cnt_tot; idx += 256) {
        int b = bno[idx];
        staging[gb[b] + (idx - lstart[b])] = sorted[idx];
    }
}

// ---------------------------------------------------------------------------
// Bin within bucket (low VGPR): per-node LDS histogram + scan -> offs;
// place (src, t) into node-sorted csrA.
// ---------------------------------------------------------------------------
__global__ __launch_bounds__(256) void bin_edges(
    const int2* __restrict__ staging, const int* __restrict__ bucketstart,
    int* __restrict__ offs, int2* __restrict__ csrA, int N)
{
    __shared__ int cnt[512], loc[512];
    const int b = blockIdx.x, t = threadIdx.x;
    const int beg = bucketstart[b], end = bucketstart[b + 1];
    const int nstart = b << 9;
    cnt[t] = 0; cnt[t + 256] = 0;
    __syncthreads();
    for (int i = beg + t; i < end; i += 256)
        atomicAdd(&cnt[(((u32)staging[i].x) >> 17) & 511], 1);
    __syncthreads();
    int v0 = cnt[t], v1 = cnt[t + 256];
    loc[t] = v0; loc[t + 256] = v1;
    __syncthreads();
    for (int off = 1; off < 512; off <<= 1) {
        int x0 = (t >= off) ? loc[t - off] : 0;
        int x1 = loc[t + 256 - off];
        __syncthreads();
        loc[t] += x0; loc[t + 256] += x1;
        __syncthreads();
    }
    int cur0 = beg + loc[t] - v0;
    int cur1 = beg + loc[t + 256] - v1;
    if (nstart + t < N) offs[nstart + t] = cur0;
    if (nstart + t + 256 < N) offs[nstart + t + 256] = cur1;
    cnt[t] = cur0; cnt[t + 256] = cur1;
    __syncthreads();
    for (int i = beg + t; i < end; i += 256) {
        int2 e = staging[i];
        int slot = atomicAdd(&cnt[(((u32)e.x) >> 17) & 511], 1);
        csrA[slot] = make_int2(e.x & 0x1ffff, e.y);
    }
}

// ---------------------------------------------------------------------------
// Temporal pass: coalesced stream over the node-sorted CSR. csrA -> (src,
// td1+b1) in place, csrB = (src, td2+b2). Keeps all sin out of the hot
// aggregates without bloating bin_edges' registers (round-10 lesson).
// ---------------------------------------------------------------------------
__global__ __launch_bounds__(256) void temporal_pass(
    int2* __restrict__ csrA, int2* __restrict__ csrB,
    const float* __restrict__ P, int E)
{
    int i = blockIdx.x * 256 + threadIdx.x;
    if (i >= E) return;
    int2 e = csrA[i];
    float tt = __int_as_float(e.y);
    float td1 = P[P_A1B], td2 = P[P_A2B];
    #pragma unroll
    for (int k = 0; k < 16; ++k) {
        td1 += __sinf(fmaf(tt, P[P_T1W + k], P[P_T1B + k])) * P[P_A1W + 128 + k];
        td2 += __sinf(fmaf(tt, P[P_T2W + k], P[P_T2B + k])) * P[P_A2W + 128 + k];
    }
    csrA[i] = make_int2(e.x, __float_as_int(td1));
    csrB[i] = make_int2(e.x, __float_as_int(td2));
}

// ---------------------------------------------------------------------------
// Aggregate: TWO nodes per wave (half-wave = 32 lanes owns one node).
// Single alpha pass (bounded alpha, clamp 80 — softmax ratio unchanged).
// LDS cache (src, e) padded to a multiple of 4 with zero-weight entries so
// phase B is ONLY the 4-loads-in-flight group loop (no tail). No block sync
// (cache is wave-private). Global fallback for deg > CAP (never fires).
// ---------------------------------------------------------------------------
template<int MODE>
__global__ __launch_bounds__(256) void aggregate(
    const int* __restrict__ offs, const int2* __restrict__ csr2,
    const u32* __restrict__ hb,
    const float* __restrict__ si, const float* __restrict__ sjv,
    const float* __restrict__ P,
    u32* __restrict__ houtb, void* __restrict__ outp,
    const int* __restrict__ flag, int n)
{
    __shared__ int2 cache[4][2][CAP];
    const int wave = threadIdx.x >> 6;
    const int lane = threadIdx.x & 63;
    const int half = lane >> 5;          // which node of the pair
    const int hl = lane & 31;            // lane within half
    const int node = blockIdx.x * 8 + wave * 2 + half;
    const bool active = node < n;
    int beg = 0, end = 0;
    if (active) { beg = offs[node]; end = offs[node + 1]; }
    const int deg = end - beg;
    int2* cw = cache[wave][half];
    const float sii = active ? si[node] : 0.f;

    // phase A: e = exp(leaky(si+sj+td)) once per edge; cache; ssum
    float ssum = 0.f;
    for (int idx = hl; idx < deg; idx += 32) {
        int2 st = csr2[beg + idx];
        float a = sii + sjv[st.x] + __int_as_float(st.y);
        a = (a > 0.f) ? a : 0.01f * a;
        float e = __expf(fminf(a, 80.f));
        if (idx < CAP) cw[idx] = make_int2(st.x, __float_as_int(e));
        ssum += e;
    }
    #pragma unroll
    for (int o = 16; o > 0; o >>= 1) ssum += __shfl_xor(ssum, o);

    // pad cache to a multiple of 4 with zero-weight entries
    const int degc = min(deg, CAP);
    const int degpad = (degc + 3) & ~3;
    if (hl < degpad - degc) cw[degc + hl] = make_int2(0, 0);

    // phase B: 32 lanes per edge row (u32 = 2 bf16 feats); 4 loads in flight
    float ax = 0.f, ay = 0.f;
    for (int j0 = 0; j0 < degpad; j0 += 4) {
        int2 s0 = cw[j0 + 0];
        int2 s1 = cw[j0 + 1];
        int2 s2 = cw[j0 + 2];
        int2 s3 = cw[j0 + 3];
        u32 p0 = hb[s0.x * 32 + hl];
        u32 p1 = hb[s1.x * 32 + hl];
        u32 p2 = hb[s2.x * 32 + hl];
        u32 p3 = hb[s3.x * 32 + hl];
        float e0 = __int_as_float(s0.y);
        float e1 = __int_as_float(s1.y);
        float e2 = __int_as_float(s2.y);
        float e3 = __int_as_float(s3.y);
        ax = fmaf(e0, __uint_as_float(p0 << 16), ax);
        ay = fmaf(e0, __uint_as_float(p0 & 0xffff0000u), ay);
        ax = fmaf(e1, __uint_as_float(p1 << 16), ax);
        ay = fmaf(e1, __uint_as_float(p1 & 0xffff0000u), ay);
        ax = fmaf(e2, __uint_as_float(p2 << 16), ax);
        ay = fmaf(e2, __uint_as_float(p2 & 0xffff0000u), ay);
        ax = fmaf(e3, __uint_as_float(p3 << 16), ax);
        ay = fmaf(e3, __uint_as_float(p3 & 0xffff0000u), ay);
    }
    // fallback for deg > CAP (statistically never: deg ~ Poisson(16))
    for (int j = CAP; j < deg; ++j) {
        int2 st = csr2[beg + j];
        float a = sii + sjv[st.x] + __int_as_float(st.y);
        a = (a > 0.f) ? a : 0.01f * a;
        float e = __expf(fminf(a, 80.f));
        u32 pk = hb[st.x * 32 + hl];
        ax = fmaf(e, __uint_as_float(pk << 16), ax);
        ay = fmaf(e, __uint_as_float(pk & 0xffff0000u), ay);
    }

    if (!active) return;
    float inv = 1.0f / (ssum + 1e-16f);

    if (MODE == 0) {
        float r0 = fmaxf(ax * inv, 0.f);
        float r1 = fmaxf(ay * inv, 0.f);
        houtb[node * 32 + hl] = (u32)f2bf(r0) | ((u32)f2bf(r1) << 16);
    } else {
        float r0 = ax * inv, r1 = ay * inv;
        float l0 = r0 * P[P_CLSW + 4 * hl]     + r1 * P[P_CLSW + 4 * hl + 2];
        float l1 = r0 * P[P_CLSW + 4 * hl + 1] + r1 * P[P_CLSW + 4 * hl + 3];
        #pragma unroll
        for (int o = 16; o > 0; o >>= 1) {
            l0 += __shfl_xor(l0, o);
            l1 += __shfl_xor(l1, o);
        }
        if (hl == 0) {
            l0 += P[P_CLSB];
            l1 += P[P_CLSB + 1];
            if (flag[0]) {
                ((float2*)outp)[node] = make_float2(l0, l1);
            } else {
                ((u32*)outp)[node] = (u32)f2bf(l0) | ((u32)f2bf(l1) << 16);
            }
        }
    }
}

// ---------------------------------------------------------------------------
extern "C" void kernel_launch(void* const* d_in, const int* in_sizes, int n_in,
                              void* d_out, int out_size, void* d_ws, size_t ws_size,
                              hipStream_t stream)
{
    const void* x    = d_in[0];
    const int*  ei   = (const int*)d_in[1];
    const void* et   = d_in[2];
    const void* l1w  = d_in[3];
    const void* l1b  = d_in[4];
    const void* a1w  = d_in[5];
    const void* a1b  = d_in[6];
    const void* t1w  = d_in[7];
    const void* t1b  = d_in[8];
    const void* l2w  = d_in[9];
    const void* l2b  = d_in[10];
    const void* a2w  = d_in[11];
    const void* a2b  = d_in[12];
    const void* t2w  = d_in[13];
    const void* t2b  = d_in[14];
    const void* clsw = d_in[15];
    const void* clsb = d_in[16];

    const int N = in_sizes[0] / 128;
    const int E = in_sizes[2];
    const int nchunks = (E + CH - 1) / CH;   // 391 (<= 512 assumed)
    const int nbkt = (N + 511) >> 9;         // buckets actually used

    char* ws = (char*)d_ws;
    size_t off = 0;
    auto A = [&](size_t bytes) -> char* {
        char* p = ws + off;
        off = (off + bytes + 255) & ~(size_t)255;
        return p;
    };
    int*   flag        = (int*)A(256);
    float* P           = (float*)A(P_TOT * 4);
    u32*   h1b         = (u32*)A((size_t)N * 32 * 4);  // bf16 h1; reused as h2
    float* si1         = (float*)A((size_t)N * 4);
    float* sj1         = (float*)A((size_t)N * 4);
    float* si2         = (float*)A((size_t)N * 4);
    float* sj2         = (float*)A((size_t)N * 4);
    int*   chunkhist   = (int*)A((size_t)nchunks * NCHB * 4);
    int*   buckettot   = (int*)A(NCHB * 4);
    int*   bucketstart = (int*)A((size_t)(NCHB + 1) * 4);
    int*   offs        = (int*)A((size_t)(N + 1) * 4);
    int2*  csrA        = (int2*)A((size_t)E * 8);
    int2*  csrB        = (int2*)A((size_t)E * 8);
    char*  unionr      = A((size_t)E * 8 < (size_t)N * 32 * 4
                           ? (size_t)N * 32 * 4 : (size_t)E * 8);
    int2*  staging     = (int2*)unionr;    // sort phase
    u32*   hagb        = (u32*)unionr;     // agg0 bf16 output (after bin)
    (void)ws_size; (void)n_in; (void)out_size;

    detect_dtype<<<1, 256, 0, stream>>>((const u32*)x, 4096, flag);

    prep_params<<<32, 256, 0, stream>>>(l1w, l1b, a1w, a1b, t1w, t1b,
                                        l2w, l2b, a2w, a2b, t2w, t2b,
                                        clsw, clsb, flag, P);

    node_gemm<128, 0><<<(N + 63) / 64, 256, 0, stream>>>(
        x, P, P_W1, P_B1, P_A1W, flag, h1b, si1, sj1, N);

    count_chunks<<<nchunks, 256, 0, stream>>>(ei + E, chunkhist, E);

    scan_chunks<<<NCHB, 256, 0, stream>>>(chunkhist, buckettot, nchunks);

    bucket_start_scan<<<1, 256, 0, stream>>>(buckettot, bucketstart, offs, N);

    place_chunks<<<nchunks, 256, 0, stream>>>(ei, et, flag, chunkhist,
                                              bucketstart, staging, E);

    bin_edges<<<nbkt, 256, 0, stream>>>(staging, bucketstart, offs, csrA, N);

    temporal_pass<<<(E + 255) / 256, 256, 0, stream>>>(csrA, csrB, P, E);

    aggregate<0><<<(N + 7) / 8, 256, 0, stream>>>(
        offs, csrA, h1b, si1, sj1, P, hagb, nullptr, flag, N);

    node_gemm<64, 2><<<(N + 63) / 64, 256, 0, stream>>>(
        hagb, P, P_W2, P_B2, P_A2W, flag, h1b, si2, sj2, N);

    aggregate<1><<<(N + 7) / 8, 256, 0, stream>>>(
        offs, csrB, h1b, si2, sj2, P, nullptr, d_out, flag, N);
}